// Round 2
// baseline (4702.115 us; speedup 1.0000x reference)
//
#include <hip/hip_runtime.h>
#include <hip/hip_bf16.h>

#define kB 128
#define kS 1024
#define kT 512
#define kV 1000
#define kE 128
#define kHE 64
#define kHD 66
#define kATT 32
#define kGE 256   // 4*kHE
#define kGD 264   // 4*kHD
#define NTHR 576  // 9 waves

typedef __attribute__((ext_vector_type(4))) float f32x4;
typedef __attribute__((ext_vector_type(8))) short bf16x8;
typedef __attribute__((ext_vector_type(8))) unsigned short u16x8;

__device__ __forceinline__ unsigned short f2bf(float f) {
  unsigned int u = __builtin_bit_cast(unsigned int, f);
  u += 0x7FFFu + ((u >> 16) & 1u);
  return (unsigned short)(u >> 16);
}
__device__ __forceinline__ float rcp_(float x) { return __builtin_amdgcn_rcpf(x); }
// sigmoid / tanh via hardware exp + rcp; branch-free, saturate correctly.
__device__ __forceinline__ float fsig(float x)  { return rcp_(1.0f + __expf(-x)); }
__device__ __forceinline__ float ftanh(float x) { return 1.0f - 2.0f * rcp_(1.0f + __expf(2.0f * x)); }

// ---------------- prep: embW = emb@Wih^T + b ; wafT4 ; biases --------------------
__global__ __launch_bounds__(256) void prep_kernel(
    const float* __restrict__ emb, const float* __restrict__ enc_Wih,
    const float* __restrict__ enc_b, const float* __restrict__ att_fc_W,
    const float* __restrict__ att_fc_b, const float* __restrict__ fin_W,
    const float* __restrict__ fin_b,
    float* __restrict__ embW, float* __restrict__ wafT4,
    float* __restrict__ abias, float* __restrict__ ainit) {
  int bid = blockIdx.x, tid = threadIdx.x;
  if (bid < kV) {
    float acc = enc_b[tid];
    const float* er = emb + bid * kE;
    const float* wr = enc_Wih + tid * kE;
    for (int e = 0; e < kE; ++e) acc += er[e] * wr[e];
    embW[bid * kGE + tid] = acc;
  } else if (bid < kV + 17) {
    // wafT4[(m4*64 + k)*4 + c] = W_af[k][m4*4+c],  W_af = att_fc_W @ fin_W  (zero-pad m>=66)
    int idx = (bid - kV) * 256 + tid;        // == (m4*64+k)*4+c by construction
    int c = idx & 3, k = (idx >> 2) & 63, m4 = idx >> 8;
    int m = m4 * 4 + c;
    float acc = 0.f;
    if (m < kHD)
      for (int e = 0; e < kE; ++e) acc += att_fc_W[k * kE + e] * fin_W[e * kHD + m];
    wafT4[idx] = acc;
  } else {
    if (tid < kHE) {
      float acc = att_fc_b[tid];
      for (int e = 0; e < kE; ++e) acc += att_fc_W[tid * kE + e] * fin_b[e];
      abias[tid] = acc;
    } else if (tid < 2 * kHE) {
      int k = tid - kHE;
      float acc = att_fc_b[k];
      for (int e = 0; e < kE; ++e) acc += emb[e] * att_fc_W[k * kE + e];
      ainit[k] = acc;
    }
  }
}

// ---------------- fused encoder + decoder: one block per batch element ----------
struct __align__(16) SMem {
  unsigned short enc[kS * kHE];   // 131072 B  bf16, XOR-swizzled rows
  float wafT4[17 * 64 * 4];       // 17408 B   W_af, AoS-float4 by output, lane-consecutive
  float gv[112];                  // 448 B     [beta(32) | h0..15 | 0000 | h16..65 | 00] pad
  float gbuf[kGD];                // 1056 B
  float betaW[8 * kATT];          // 1024 B
  float hdec[68];                 // 272 B
  float aa[kHE];                  // 256 B
  float hbuf[kHE];                // 256 B
  int   toks[kS];                 // 4096 B
};  // ~155.9 KB

__global__ __launch_bounds__(NTHR, 2) void attlstm_main(
    const int* __restrict__ x, const float* __restrict__ embW,
    const float* __restrict__ enc_Whh, const float* __restrict__ att_w_W,
    const float* __restrict__ att_w_b, const float* __restrict__ dec_Wih,
    const float* __restrict__ dec_Whh, const float* __restrict__ dec_b,
    const float* __restrict__ wafT4_ws, const float* __restrict__ abias_ws,
    const float* __restrict__ ainit_ws, float* __restrict__ out) {
  __shared__ SMem sm;
  const int b = blockIdx.x;
  const int t = threadIdx.x;
  const int lane = t & 63;
  const int wv = t >> 6;

  // ---- setup
  for (int i = t; i < kS; i += NTHR) sm.toks[i] = x[b * kS + i];
  if (t < kHE) sm.hbuf[t] = 0.0f;

  const int j_enc = t >> 1, hh = t & 1;
  float whhE[32];
  if (t < 512) {
    #pragma unroll
    for (int k = 0; k < 32; ++k) whhE[k] = enc_Whh[j_enc * kHE + hh * 32 + k];
  }
  __syncthreads();

  // ---- encoder LSTM over S steps
  float cE = 0.0f;
  float gx = (t < 512 && hh == 0) ? embW[sm.toks[0] * kGE + j_enc] : 0.0f;
  for (int s = 0; s < kS; ++s) {
    int snx = (s + 1 < kS) ? (s + 1) : s;
    float gxn = (t < 512 && hh == 0) ? embW[sm.toks[snx] * kGE + j_enc] : 0.0f;
    if (t < 512) {
      const f32x4* h4 = (const f32x4*)sm.hbuf;
      float acc = 0.0f;
      #pragma unroll
      for (int q = 0; q < 8; ++q) {
        f32x4 hv = h4[hh * 8 + q];
        acc += hv.x * whhE[q*4+0] + hv.y * whhE[q*4+1] + hv.z * whhE[q*4+2] + hv.w * whhE[q*4+3];
      }
      acc += __shfl_xor(acc, 1);
      if (hh == 0) sm.gbuf[j_enc] = acc + gx;
    }
    __syncthreads();
    if (t < kHE) {
      float gi = sm.gbuf[t], gf = sm.gbuf[64 + t], gg = sm.gbuf[128 + t], go = sm.gbuf[192 + t];
      cE = fsig(gf) * cE + fsig(gi) * ftanh(gg);
      float h = fsig(go) * ftanh(cE);
      sm.hbuf[t] = h;
      sm.enc[s * kHE + ((((t >> 3) ^ (s & 7)) << 3) | (t & 7))] = f2bf(h);
    }
    __syncthreads();
    gx = gxn;
  }

  // ---- decoder setup
  for (int i = t; i < 17 * 64 * 4; i += NTHR) sm.wafT4[i] = wafT4_ws[i];
  if (t < kHE) sm.aa[t] = ainit_ws[t];
  if (t < 112) sm.gv[t] = 0.0f;
  if (t < 68) sm.hdec[t] = 0.0f;

  const int lr = lane & 15;
  const int g = lane >> 4;
  float wreg[2][2][8];
  #pragma unroll
  for (int mt = 0; mt < 2; ++mt)
    #pragma unroll
    for (int kc = 0; kc < 2; ++kc)
      #pragma unroll
      for (int jj = 0; jj < 8; ++jj)
        wreg[mt][kc][jj] = att_w_W[(mt * 16 + lr) * kHE + kc * 32 + g * 8 + jj];
  float wbreg[2][4];
  #pragma unroll
  for (int mt = 0; mt < 2; ++mt)
    #pragma unroll
    for (int r = 0; r < 4; ++r) wbreg[mt][r] = att_w_b[mt * 16 + g * 4 + r];

  // decoder gates: 2 threads per gate j, 52-reg weight slice each (no spills)
  float wg[52];
  float dbv = 0.0f;
  const int jg = t >> 1;          // gate index for t < 528
  if (t < 2 * kGD) {
    #pragma unroll
    for (int q = 0; q < 52; ++q) wg[q] = 0.0f;
    if (hh == 0) {
      #pragma unroll
      for (int m = 0; m < 32; ++m) wg[m] = dec_Wih[jg * kATT + m];
      #pragma unroll
      for (int m = 0; m < 16; ++m) wg[32 + m] = dec_Whh[jg * kHD + m];
      dbv = dec_b[jg];
    } else {
      #pragma unroll
      for (int m = 0; m < 50; ++m) wg[m] = dec_Whh[jg * kHD + 16 + m];
    }
  }
  float abias = (t < kHE) ? abias_ws[t] : 0.0f;

  float cD = 0.0f;
  __syncthreads();

  // ---- decoder loop
  const int sbase = wv * 128;
  for (int step = 0; step < kT; ++step) {
    if (wv < 8) {
      // A-fragments: V[a][k] = att_w_W[a][k] * aa[k]  (bf16, packed via cvt_pk)
      const f32x4* aap = (const f32x4*)sm.aa;
      bf16x8 af[2][2];
      #pragma unroll
      for (int kc = 0; kc < 2; ++kc) {
        f32x4 a0 = aap[kc * 8 + g * 2];
        f32x4 a1 = aap[kc * 8 + g * 2 + 1];
        float av[8] = {a0.x, a0.y, a0.z, a0.w, a1.x, a1.y, a1.z, a1.w};
        #pragma unroll
        for (int mt = 0; mt < 2; ++mt) {
          union { bf16x8 v; __hip_bfloat162 h2[4]; } tmp;
          #pragma unroll
          for (int p = 0; p < 4; ++p)
            tmp.h2[p] = __float22bfloat162_rn(
                make_float2(wreg[mt][kc][2*p] * av[2*p], wreg[mt][kc][2*p+1] * av[2*p+1]));
          af[mt][kc] = tmp.v;
        }
      }

      float betaAcc[2][4] = {};
      float amax = 0.0f;
      #pragma unroll
      for (int nt = 0; nt < 8; ++nt) {
        int s = sbase + nt * 16 + lr;
        int sw = s & 7;
        union { u16x8 u; bf16x8 b; } e0, e1;
        e0.u = *(const u16x8*)&sm.enc[s * kHE + ((g ^ sw) << 3)];
        e1.u = *(const u16x8*)&sm.enc[s * kHE + (((4 + g) ^ sw) << 3)];
        f32x4 z = {0.f, 0.f, 0.f, 0.f};
        f32x4 acc0 = __builtin_amdgcn_mfma_f32_16x16x32_bf16(af[0][0], e0.b, z, 0, 0, 0);
        acc0 = __builtin_amdgcn_mfma_f32_16x16x32_bf16(af[0][1], e1.b, acc0, 0, 0, 0);
        f32x4 acc1 = __builtin_amdgcn_mfma_f32_16x16x32_bf16(af[1][0], e0.b, z, 0, 0, 0);
        acc1 = __builtin_amdgcn_mfma_f32_16x16x32_bf16(af[1][1], e1.b, acc1, 0, 0, 0);
        float u0[4], u1[4], dsum = 0.f;
        #pragma unroll
        for (int r = 0; r < 4; ++r) {
          float x0 = acc0[r] + wbreg[0][r];
          float x1 = acc1[r] + wbreg[1][r];
          amax = fmaxf(amax, fmaxf(__builtin_fabsf(x0), __builtin_fabsf(x1)));
          u0[r] = __expf(x0 * __builtin_fmaf(x0 * x0, -0.33333334f, 1.0f));  // e^tanh(x)
          u1[r] = __expf(x1 * __builtin_fmaf(x1 * x1, -0.33333334f, 1.0f));
          dsum += u0[r] + u1[r];
        }
        dsum += __shfl_xor(dsum, 16);
        dsum += __shfl_xor(dsum, 32);
        float invd = rcp_(dsum);
        #pragma unroll
        for (int r = 0; r < 4; ++r) {
          betaAcc[0][r] += u0[r] * invd;
          betaAcc[1][r] += u1[r] * invd;
        }
      }
      if (__builtin_expect(__any(amax > 0.35f), 0)) {
        // exact fallback (rare): redo the sweep with libm exp(tanh())
        #pragma unroll
        for (int mt = 0; mt < 2; ++mt)
          #pragma unroll
          for (int r = 0; r < 4; ++r) betaAcc[mt][r] = 0.f;
        for (int nt = 0; nt < 8; ++nt) {
          int s = sbase + nt * 16 + lr;
          int sw = s & 7;
          union { u16x8 u; bf16x8 b; } e0, e1;
          e0.u = *(const u16x8*)&sm.enc[s * kHE + ((g ^ sw) << 3)];
          e1.u = *(const u16x8*)&sm.enc[s * kHE + (((4 + g) ^ sw) << 3)];
          f32x4 z = {0.f, 0.f, 0.f, 0.f};
          f32x4 acc0 = __builtin_amdgcn_mfma_f32_16x16x32_bf16(af[0][0], e0.b, z, 0, 0, 0);
          acc0 = __builtin_amdgcn_mfma_f32_16x16x32_bf16(af[0][1], e1.b, acc0, 0, 0, 0);
          f32x4 acc1 = __builtin_amdgcn_mfma_f32_16x16x32_bf16(af[1][0], e0.b, z, 0, 0, 0);
          acc1 = __builtin_amdgcn_mfma_f32_16x16x32_bf16(af[1][1], e1.b, acc1, 0, 0, 0);
          float u0[4], u1[4], dsum = 0.f;
          for (int r = 0; r < 4; ++r) {
            u0[r] = __expf(tanhf(acc0[r] + wbreg[0][r]));
            u1[r] = __expf(tanhf(acc1[r] + wbreg[1][r]));
            dsum += u0[r] + u1[r];
          }
          dsum += __shfl_xor(dsum, 16);
          dsum += __shfl_xor(dsum, 32);
          float invd = rcp_(dsum);
          for (int r = 0; r < 4; ++r) {
            betaAcc[0][r] += u0[r] * invd;
            betaAcc[1][r] += u1[r] * invd;
          }
        }
      }
      #pragma unroll
      for (int mt = 0; mt < 2; ++mt)
        #pragma unroll
        for (int r = 0; r < 4; ++r) {
          float v = betaAcc[mt][r];
          v += __shfl_xor(v, 1);
          v += __shfl_xor(v, 2);
          v += __shfl_xor(v, 4);
          v += __shfl_xor(v, 8);
          if (lr == 0) sm.betaW[wv * kATT + mt * 16 + g * 4 + r] = v;
        }
    }
    __syncthreads();
    if (t < kATT) {
      float sum = 0.f;
      #pragma unroll
      for (int w = 0; w < 8; ++w) sum += sm.betaW[w * kATT + t];
      sm.gv[t] = sum;
    }
    __syncthreads();
    if (t < 2 * kGD) {
      float gacc = dbv;
      const f32x4* gvp = (const f32x4*)(sm.gv + hh * 52);
      #pragma unroll
      for (int q = 0; q < 13; ++q) {
        f32x4 v = gvp[q];
        gacc += v.x * wg[q*4+0] + v.y * wg[q*4+1] + v.z * wg[q*4+2] + v.w * wg[q*4+3];
      }
      gacc += __shfl_xor(gacc, 1);
      if (hh == 0) sm.gbuf[jg] = gacc;
    }
    __syncthreads();
    if (t < kHD) {
      float gi = sm.gbuf[t], gf = sm.gbuf[kHD + t], gg = sm.gbuf[2*kHD + t], go = sm.gbuf[3*kHD + t];
      cD = fsig(gf) * cD + fsig(gi) * ftanh(gg);
      float h = fsig(go) * ftanh(cD);
      sm.hdec[t] = h;
      if (t < 16) sm.gv[32 + t] = h; else sm.gv[36 + t] = h;   // 52 + (t-16)
      out[(b * kT + step) * kHD + t] = h;
    }
    __syncthreads();
    if (t < kHE) {
      float v = abias;
      const f32x4* hp = (const f32x4*)sm.hdec;
      const f32x4* wp = (const f32x4*)sm.wafT4;
      #pragma unroll
      for (int m4 = 0; m4 < 17; ++m4) {
        f32x4 hv = hp[m4];
        f32x4 w4 = wp[m4 * 64 + t];
        v += hv.x * w4.x + hv.y * w4.y + hv.z * w4.z + hv.w * w4.w;
      }
      sm.aa[t] = v;
    }
    __syncthreads();
  }
}

extern "C" void kernel_launch(void* const* d_in, const int* in_sizes, int n_in,
                              void* d_out, int out_size, void* d_ws, size_t ws_size,
                              hipStream_t stream) {
  const int*   x        = (const int*)d_in[0];
  const float* emb      = (const float*)d_in[2];
  const float* enc_Wih  = (const float*)d_in[3];
  const float* enc_Whh  = (const float*)d_in[4];
  const float* enc_b    = (const float*)d_in[5];
  const float* att_fc_W = (const float*)d_in[6];
  const float* att_fc_b = (const float*)d_in[7];
  const float* att_w_W  = (const float*)d_in[8];
  const float* att_w_b  = (const float*)d_in[9];
  const float* dec_Wih  = (const float*)d_in[10];
  const float* dec_Whh  = (const float*)d_in[11];
  const float* dec_b    = (const float*)d_in[12];
  const float* fin_W    = (const float*)d_in[13];
  const float* fin_b    = (const float*)d_in[14];
  float* out = (float*)d_out;

  float* embW  = (float*)d_ws;             // 1000*256
  float* wafT4 = embW + kV * kGE;          // 17*64*4
  float* abias = wafT4 + 17 * 64 * 4;      // 64
  float* ainit = abias + kHE;              // 64

  prep_kernel<<<dim3(kV + 17 + 1), dim3(256), 0, stream>>>(
      emb, enc_Wih, enc_b, att_fc_W, att_fc_b, fin_W, fin_b, embW, wafT4, abias, ainit);
  attlstm_main<<<dim3(kB), dim3(NTHR), 0, stream>>>(
      x, embW, enc_Whh, att_w_W, att_w_b, dec_Wih, dec_Whh, dec_b,
      wafT4, abias, ainit, out);
}

// Round 4
// 4607.615 us; speedup vs baseline: 1.0205x; 1.0205x over previous
//
#include <hip/hip_runtime.h>
#include <hip/hip_bf16.h>

#define kB 128
#define kS 1024
#define kT 512
#define kV 1000
#define kE 128
#define kHE 64
#define kHD 66
#define kATT 32
#define kGE 256   // 4*kHE
#define kGD 264   // 4*kHD

typedef __attribute__((ext_vector_type(4))) float f32x4;
typedef __attribute__((ext_vector_type(8))) short bf16x8;
typedef __attribute__((ext_vector_type(8))) unsigned short u16x8;

__device__ __forceinline__ unsigned short f2bf(float f) {
  unsigned int u = __builtin_bit_cast(unsigned int, f);
  u += 0x7FFFu + ((u >> 16) & 1u);
  return (unsigned short)(u >> 16);
}
__device__ __forceinline__ float rcp_(float x) { return __builtin_amdgcn_rcpf(x); }
__device__ __forceinline__ float fsig(float x)  { return rcp_(1.0f + __expf(-x)); }
__device__ __forceinline__ float ftanh(float x) { return 1.0f - 2.0f * rcp_(1.0f + __expf(2.0f * x)); }

// ---------------------------------------------------------------------------
// prep: embW (f32), bf16 MFMA B-fragments for enc_Whh / [dec_Wih|dec_Whh] / W_af,
// folded biases. Fragment layout: frag[((tile*KS + ks)*64 + lane)*8 + jj] =
// B[k = ks*32 + (lane>>4)*8 + jj][col = lane&15]  (col -> output index tile*16+col)
// ---------------------------------------------------------------------------
__global__ __launch_bounds__(256) void prep_kernel(
    const float* __restrict__ emb, const float* __restrict__ enc_Wih,
    const float* __restrict__ enc_b, const float* __restrict__ enc_Whh,
    const float* __restrict__ att_fc_W, const float* __restrict__ att_fc_b,
    const float* __restrict__ fin_W, const float* __restrict__ fin_b,
    const float* __restrict__ dec_Wih, const float* __restrict__ dec_Whh,
    const float* __restrict__ dec_b,
    float* __restrict__ embW, unsigned short* __restrict__ decF,
    unsigned short* __restrict__ encF, unsigned short* __restrict__ afF,
    float* __restrict__ dbias, float* __restrict__ abias,
    float* __restrict__ ainit) {
  int bid = blockIdx.x, tid = threadIdx.x;
  if (bid < kV) {
    float acc = enc_b[tid];
    const float* er = emb + bid * kE;
    const float* wr = enc_Wih + tid * kE;
    for (int e = 0; e < kE; ++e) acc += er[e] * wr[e];
    embW[bid * kGE + tid] = acc;
  } else if (bid == kV) {
    // decF: 17 tiles x 4 ksteps, W = [dec_Wih | dec_Whh | 0pad], j<264
    for (int i = tid; i < 17 * 4 * 64 * 8; i += 256) {
      int jj = i & 7, lane = (i >> 3) & 63, ts = i >> 9;
      int tile = ts >> 2, ks = ts & 3;
      int j = tile * 16 + (lane & 15);
      int k = ks * 32 + ((lane >> 4) << 3) + jj;
      float v = 0.f;
      if (j < kGD) {
        if (k < 32) v = dec_Wih[j * kATT + k];
        else if (k < 98) v = dec_Whh[j * kHD + (k - 32)];
      }
      decF[i] = f2bf(v);
    }
  } else if (bid == kV + 1) {
    // encF: 16 tiles x 2 ksteps, B[k][j] = enc_Whh[j][k]
    for (int i = tid; i < 16 * 2 * 64 * 8; i += 256) {
      int jj = i & 7, lane = (i >> 3) & 63, ts = i >> 9;
      int tile = ts >> 1, ks = ts & 1;
      int j = tile * 16 + (lane & 15);
      int k = ks * 32 + ((lane >> 4) << 3) + jj;
      encF[i] = f2bf(enc_Whh[j * kHE + k]);
    }
  } else if (bid == kV + 2) {
    // afF: 4 tiles x 3 ksteps, B[m][aidx] = W_af[aidx][m] = sum_e att_fc_W[aidx][e] fin_W[e][m]
    for (int i = tid; i < 4 * 3 * 64 * 8; i += 256) {
      int jj = i & 7, lane = (i >> 3) & 63, ts = i >> 9;
      int tile = ts / 3, ks = ts - tile * 3;
      int aidx = tile * 16 + (lane & 15);
      int m = ks * 32 + ((lane >> 4) << 3) + jj;
      float v = 0.f;
      if (m < kHD)
        for (int e = 0; e < kE; ++e) v += att_fc_W[aidx * kE + e] * fin_W[e * kHD + m];
      afF[i] = f2bf(v);
    }
  } else if (bid == kV + 3) {
    // dbias' = dec_b + 32 * rowsum(dec_Wih)   (beta fed centered at 32)
    // NOTE: kGD=264 > 256 threads -> strided loop (R3 bug: tail 256..263 was
    // never written -> poisoned o-gate bias for outputs 58..65, absmax 0.49)
    for (int j = tid; j < kGD; j += 256) {
      float s = 0.f;
      for (int m = 0; m < kATT; ++m) s += dec_Wih[j * kATT + m];
      dbias[j] = dec_b[j] + 32.0f * s;
    }
  } else {
    if (tid < kHE) {
      float acc = att_fc_b[tid];
      for (int e = 0; e < kE; ++e) acc += att_fc_W[tid * kE + e] * fin_b[e];
      abias[tid] = acc;
    } else if (tid < 2 * kHE) {
      int a = tid - kHE;
      float acc = att_fc_b[a];
      for (int e = 0; e < kE; ++e) acc += emb[e] * att_fc_W[a * kE + e];
      ainit[a] = acc;
    }
  }
}

// ---------------------------------------------------------------------------
// encoder: 1 block / batch element, 256 threads (4 waves x 4 tiles).
// Writes swizzled bf16 h-states into out[b-region] (decoder stages from there,
// and overwrites it afterwards -- deterministic per replay).
// ---------------------------------------------------------------------------
__global__ __launch_bounds__(256, 1) void enc_kernel(
    const int* __restrict__ x, const float* __restrict__ embW,
    const unsigned short* __restrict__ encF, float* __restrict__ out) {
  __shared__ struct __align__(16) {
    unsigned short xe[64];
    float gbuf[kGE];
    int toks[kS];
  } sm;
  const int b = blockIdx.x, t = threadIdx.x, lane = t & 63, wv = t >> 6;

  for (int i = t; i < kS; i += 256) sm.toks[i] = x[b * kS + i];
  if (t < 64) sm.xe[t] = 0;

  u16x8 eQ[4][2];
  #pragma unroll
  for (int q = 0; q < 4; ++q)
    #pragma unroll
    for (int ks = 0; ks < 2; ++ks)
      eQ[q][ks] = *(const u16x8*)&encF[(((wv * 4 + q) * 2 + ks) * 64 + lane) * 8];
  __syncthreads();

  float gx0 = 0, gx1 = 0, gx2 = 0, gx3 = 0;
  if (lane < 16) {
    int tok = sm.toks[0];
    gx0 = embW[tok * kGE + wv * 64 + 0 + lane];
    gx1 = embW[tok * kGE + wv * 64 + 16 + lane];
    gx2 = embW[tok * kGE + wv * 64 + 32 + lane];
    gx3 = embW[tok * kGE + wv * 64 + 48 + lane];
  }
  float cE = 0.0f;
  unsigned short* eg = (unsigned short*)(out + (size_t)b * (kT * kHD));

  for (int s = 0; s < kS; ++s) {
    union { u16x8 u; bf16x8 v; } xa0, xa1;
    xa0.u = *(const u16x8*)&sm.xe[(lane >> 4) << 3];
    xa1.u = *(const u16x8*)&sm.xe[32 + ((lane >> 4) << 3)];
    // prefetch next-token input transforms
    float gn0 = 0, gn1 = 0, gn2 = 0, gn3 = 0;
    int tokn = sm.toks[(s + 1 < kS) ? (s + 1) : s];
    if (lane < 16) {
      gn0 = embW[tokn * kGE + wv * 64 + 0 + lane];
      gn1 = embW[tokn * kGE + wv * 64 + 16 + lane];
      gn2 = embW[tokn * kGE + wv * 64 + 32 + lane];
      gn3 = embW[tokn * kGE + wv * 64 + 48 + lane];
    }
    f32x4 z = {0.f, 0.f, 0.f, 0.f};
    f32x4 a0 = __builtin_amdgcn_mfma_f32_16x16x32_bf16(xa0.v, eQ[0][0], z, 0, 0, 0);
    a0 = __builtin_amdgcn_mfma_f32_16x16x32_bf16(xa1.v, eQ[0][1], a0, 0, 0, 0);
    f32x4 a1 = __builtin_amdgcn_mfma_f32_16x16x32_bf16(xa0.v, eQ[1][0], z, 0, 0, 0);
    a1 = __builtin_amdgcn_mfma_f32_16x16x32_bf16(xa1.v, eQ[1][1], a1, 0, 0, 0);
    f32x4 a2 = __builtin_amdgcn_mfma_f32_16x16x32_bf16(xa0.v, eQ[2][0], z, 0, 0, 0);
    a2 = __builtin_amdgcn_mfma_f32_16x16x32_bf16(xa1.v, eQ[2][1], a2, 0, 0, 0);
    f32x4 a3 = __builtin_amdgcn_mfma_f32_16x16x32_bf16(xa0.v, eQ[3][0], z, 0, 0, 0);
    a3 = __builtin_amdgcn_mfma_f32_16x16x32_bf16(xa1.v, eQ[3][1], a3, 0, 0, 0);
    if (lane < 16) {
      sm.gbuf[wv * 64 + 0 + lane]  = a0[0] + gx0;
      sm.gbuf[wv * 64 + 16 + lane] = a1[0] + gx1;
      sm.gbuf[wv * 64 + 32 + lane] = a2[0] + gx2;
      sm.gbuf[wv * 64 + 48 + lane] = a3[0] + gx3;
    }
    __syncthreads();
    if (t < 64) {
      float gi = sm.gbuf[t], gf = sm.gbuf[64 + t], gg = sm.gbuf[128 + t], go = sm.gbuf[192 + t];
      cE = fsig(gf) * cE + fsig(gi) * ftanh(gg);
      float h = fsig(go) * ftanh(cE);
      unsigned short hb = f2bf(h);
      sm.xe[t] = hb;
      eg[s * 64 + ((((t >> 3) ^ (s & 7)) << 3) | (t & 7))] = hb;
    }
    __syncthreads();
    gx0 = gn0; gx1 = gn1; gx2 = gn2; gx3 = gn3;
  }
}

// ---------------------------------------------------------------------------
// decoder: 1 block / batch element, 1024 threads (16 waves).
// ---------------------------------------------------------------------------
struct __align__(16) DSm {
  unsigned short enc[kS * kHE];   // 131072 B  swizzled bf16
  unsigned short xv[128];         // x-vector: [beta-32 (32) | h (66) | 0 pad]
  float aa[64];
  float betaW[16][32];
  float gbuf[kGD];
};  // ~134.7 KB

__global__ __launch_bounds__(1024, 1) void dec_kernel(
    const float* __restrict__ att_w_W, const float* __restrict__ att_w_b,
    const unsigned short* __restrict__ decF, const unsigned short* __restrict__ afF,
    const float* __restrict__ dbias_ws, const float* __restrict__ abias_ws,
    const float* __restrict__ ainit_ws, float* __restrict__ out) {
  __shared__ DSm sm;
  const int b = blockIdx.x, t = threadIdx.x, lane = t & 63, wv = t >> 6;
  const int lr = lane & 15, g = lane >> 4;

  // stage encoder states (written by enc_kernel into this b's out region)
  {
    const u16x8* src = (const u16x8*)(out + (size_t)b * (kT * kHD));
    u16x8* dst = (u16x8*)sm.enc;
    #pragma unroll
    for (int i = 0; i < 8; ++i) dst[t + i * 1024] = src[t + i * 1024];
  }

  float wreg[2][2][8];
  #pragma unroll
  for (int mt = 0; mt < 2; ++mt)
    #pragma unroll
    for (int kc = 0; kc < 2; ++kc)
      #pragma unroll
      for (int jj = 0; jj < 8; ++jj)
        wreg[mt][kc][jj] = att_w_W[(mt * 16 + lr) * kHE + kc * 32 + g * 8 + jj];
  float wbreg[2][4];
  #pragma unroll
  for (int mt = 0; mt < 2; ++mt)
    #pragma unroll
    for (int r = 0; r < 4; ++r) wbreg[mt][r] = att_w_b[mt * 16 + g * 4 + r];

  u16x8 dQ[4], dQ2[4], aQ[3];
  #pragma unroll
  for (int ks = 0; ks < 4; ++ks)
    dQ[ks] = *(const u16x8*)&decF[((wv * 4 + ks) * 64 + lane) * 8];
  if (wv == 15) {
    #pragma unroll
    for (int ks = 0; ks < 4; ++ks)
      dQ2[ks] = *(const u16x8*)&decF[((16 * 4 + ks) * 64 + lane) * 8];
  }
  if (wv < 4) {
    #pragma unroll
    for (int ks = 0; ks < 3; ++ks)
      aQ[ks] = *(const u16x8*)&afF[((wv * 3 + ks) * 64 + lane) * 8];
  }
  float dbr = (lane < 16) ? dbias_ws[wv * 16 + lane] : 0.f;
  float dbr2 = (wv == 15 && lane < 8) ? dbias_ws[256 + lane] : 0.f;
  float abr = (wv < 4 && lane < 16) ? abias_ws[wv * 16 + lane] : 0.f;

  if (t < 128) sm.xv[t] = 0;
  if (t < 64) sm.aa[t] = ainit_ws[t];
  float cD = 0.0f;
  __syncthreads();

  const int sbase = wv * 64;
  for (int step = 0; step < kT; ++step) {
    // ---- P1: attention sweep (scores + softmax + beta partials), all 16 waves
    {
      const f32x4* aap = (const f32x4*)sm.aa;
      bf16x8 af[2][2];
      #pragma unroll
      for (int kc = 0; kc < 2; ++kc) {
        f32x4 a0v = aap[kc * 8 + g * 2];
        f32x4 a1v = aap[kc * 8 + g * 2 + 1];
        float av[8] = {a0v.x, a0v.y, a0v.z, a0v.w, a1v.x, a1v.y, a1v.z, a1v.w};
        #pragma unroll
        for (int mt = 0; mt < 2; ++mt) {
          union { bf16x8 v; __hip_bfloat162 h2[4]; } tmp;
          #pragma unroll
          for (int p = 0; p < 4; ++p)
            tmp.h2[p] = __float22bfloat162_rn(
                make_float2(wreg[mt][kc][2*p] * av[2*p], wreg[mt][kc][2*p+1] * av[2*p+1]));
          af[mt][kc] = tmp.v;
        }
      }
      float betaAcc[2][4] = {};
      float amax = 0.0f;
      #pragma unroll
      for (int nt = 0; nt < 4; ++nt) {
        int s = sbase + nt * 16 + lr;
        int sw = s & 7;
        union { u16x8 u; bf16x8 bv; } e0, e1;
        e0.u = *(const u16x8*)&sm.enc[s * kHE + ((g ^ sw) << 3)];
        e1.u = *(const u16x8*)&sm.enc[s * kHE + (((4 + g) ^ sw) << 3)];
        f32x4 z = {0.f, 0.f, 0.f, 0.f};
        f32x4 acc0 = __builtin_amdgcn_mfma_f32_16x16x32_bf16(af[0][0], e0.bv, z, 0, 0, 0);
        acc0 = __builtin_amdgcn_mfma_f32_16x16x32_bf16(af[0][1], e1.bv, acc0, 0, 0, 0);
        f32x4 acc1 = __builtin_amdgcn_mfma_f32_16x16x32_bf16(af[1][0], e0.bv, z, 0, 0, 0);
        acc1 = __builtin_amdgcn_mfma_f32_16x16x32_bf16(af[1][1], e1.bv, acc1, 0, 0, 0);
        float u0[4], u1[4], dsum = 0.f;
        #pragma unroll
        for (int r = 0; r < 4; ++r) {
          float x0 = acc0[r] + wbreg[0][r];
          float x1 = acc1[r] + wbreg[1][r];
          amax = fmaxf(amax, fmaxf(__builtin_fabsf(x0), __builtin_fabsf(x1)));
          u0[r] = __expf(x0 * __builtin_fmaf(x0 * x0, -0.33333334f, 1.0f));
          u1[r] = __expf(x1 * __builtin_fmaf(x1 * x1, -0.33333334f, 1.0f));
          dsum += u0[r] + u1[r];
        }
        dsum += __shfl_xor(dsum, 16);
        dsum += __shfl_xor(dsum, 32);
        float invd = rcp_(dsum);
        #pragma unroll
        for (int r = 0; r < 4; ++r) {
          betaAcc[0][r] += u0[r] * invd;
          betaAcc[1][r] += u1[r] * invd;
        }
      }
      if (__builtin_expect(__any(amax > 0.35f), 0)) {
        #pragma unroll
        for (int mt = 0; mt < 2; ++mt)
          #pragma unroll
          for (int r = 0; r < 4; ++r) betaAcc[mt][r] = 0.f;
        for (int nt = 0; nt < 4; ++nt) {
          int s = sbase + nt * 16 + lr;
          int sw = s & 7;
          union { u16x8 u; bf16x8 bv; } e0, e1;
          e0.u = *(const u16x8*)&sm.enc[s * kHE + ((g ^ sw) << 3)];
          e1.u = *(const u16x8*)&sm.enc[s * kHE + (((4 + g) ^ sw) << 3)];
          f32x4 z = {0.f, 0.f, 0.f, 0.f};
          f32x4 acc0 = __builtin_amdgcn_mfma_f32_16x16x32_bf16(af[0][0], e0.bv, z, 0, 0, 0);
          acc0 = __builtin_amdgcn_mfma_f32_16x16x32_bf16(af[0][1], e1.bv, acc0, 0, 0, 0);
          f32x4 acc1 = __builtin_amdgcn_mfma_f32_16x16x32_bf16(af[1][0], e0.bv, z, 0, 0, 0);
          acc1 = __builtin_amdgcn_mfma_f32_16x16x32_bf16(af[1][1], e1.bv, acc1, 0, 0, 0);
          float u0[4], u1[4], dsum = 0.f;
          for (int r = 0; r < 4; ++r) {
            u0[r] = __expf(tanhf(acc0[r] + wbreg[0][r]));
            u1[r] = __expf(tanhf(acc1[r] + wbreg[1][r]));
            dsum += u0[r] + u1[r];
          }
          dsum += __shfl_xor(dsum, 16);
          dsum += __shfl_xor(dsum, 32);
          float invd = rcp_(dsum);
          for (int r = 0; r < 4; ++r) {
            betaAcc[0][r] += u0[r] * invd;
            betaAcc[1][r] += u1[r] * invd;
          }
        }
      }
      #pragma unroll
      for (int mt = 0; mt < 2; ++mt)
        #pragma unroll
        for (int r = 0; r < 4; ++r) {
          float v = betaAcc[mt][r];
          v += __shfl_xor(v, 1);
          v += __shfl_xor(v, 2);
          v += __shfl_xor(v, 4);
          v += __shfl_xor(v, 8);
          if (lr == 0) sm.betaW[wv][mt * 16 + g * 4 + r] = v;
        }
    }
    __syncthreads();
    // ---- P2: beta reduce -> xv (centered bf16)
    if (t < kATT) {
      float sb = 0.f;
      #pragma unroll
      for (int w = 0; w < 16; ++w) sb += sm.betaW[w][t];
      sm.xv[t] = f2bf(sb - 32.0f);
    }
    __syncthreads();
    // ---- P3: decoder gates via MFMA (wave w -> tile w; wave 15 also tile 16)
    {
      union { u16x8 u; bf16x8 v; } xg0, xg1, xg2, xg3;
      xg0.u = *(const u16x8*)&sm.xv[(g << 3)];
      xg1.u = *(const u16x8*)&sm.xv[32 + (g << 3)];
      xg2.u = *(const u16x8*)&sm.xv[64 + (g << 3)];
      xg3.u = *(const u16x8*)&sm.xv[96 + (g << 3)];
      f32x4 z = {0.f, 0.f, 0.f, 0.f};
      f32x4 ga = __builtin_amdgcn_mfma_f32_16x16x32_bf16(xg0.v, dQ[0], z, 0, 0, 0);
      ga = __builtin_amdgcn_mfma_f32_16x16x32_bf16(xg1.v, dQ[1], ga, 0, 0, 0);
      ga = __builtin_amdgcn_mfma_f32_16x16x32_bf16(xg2.v, dQ[2], ga, 0, 0, 0);
      ga = __builtin_amdgcn_mfma_f32_16x16x32_bf16(xg3.v, dQ[3], ga, 0, 0, 0);
      if (lane < 16) sm.gbuf[wv * 16 + lane] = ga[0] + dbr;
      if (wv == 15) {
        f32x4 gb = __builtin_amdgcn_mfma_f32_16x16x32_bf16(xg0.v, dQ2[0], z, 0, 0, 0);
        gb = __builtin_amdgcn_mfma_f32_16x16x32_bf16(xg1.v, dQ2[1], gb, 0, 0, 0);
        gb = __builtin_amdgcn_mfma_f32_16x16x32_bf16(xg2.v, dQ2[2], gb, 0, 0, 0);
        gb = __builtin_amdgcn_mfma_f32_16x16x32_bf16(xg3.v, dQ2[3], gb, 0, 0, 0);
        if (lane < 8) sm.gbuf[256 + lane] = gb[0] + dbr2;
      }
    }
    __syncthreads();
    // ---- P4: LSTM cell + output + h -> xv
    if (t < kHD) {
      float gi = sm.gbuf[t], gf = sm.gbuf[kHD + t], gg = sm.gbuf[2 * kHD + t], go = sm.gbuf[3 * kHD + t];
      cD = fsig(gf) * cD + fsig(gi) * ftanh(gg);
      float h = fsig(go) * ftanh(cD);
      sm.xv[32 + t] = f2bf(h);
      out[((size_t)b * kT + step) * kHD + t] = h;
    }
    __syncthreads();
    // ---- P5: a-update via MFMA (waves 0-3)
    if (wv < 4) {
      union { u16x8 u; bf16x8 v; } y0, y1, y2;
      y0.u = *(const u16x8*)&sm.xv[32 + (g << 3)];
      y1.u = *(const u16x8*)&sm.xv[64 + (g << 3)];
      y2.u = *(const u16x8*)&sm.xv[96 + (g << 3)];
      f32x4 z = {0.f, 0.f, 0.f, 0.f};
      f32x4 aacc = __builtin_amdgcn_mfma_f32_16x16x32_bf16(y0.v, aQ[0], z, 0, 0, 0);
      aacc = __builtin_amdgcn_mfma_f32_16x16x32_bf16(y1.v, aQ[1], aacc, 0, 0, 0);
      aacc = __builtin_amdgcn_mfma_f32_16x16x32_bf16(y2.v, aQ[2], aacc, 0, 0, 0);
      if (lane < 16) sm.aa[wv * 16 + lane] = aacc[0] + abr;
    }
    __syncthreads();
  }
}

extern "C" void kernel_launch(void* const* d_in, const int* in_sizes, int n_in,
                              void* d_out, int out_size, void* d_ws, size_t ws_size,
                              hipStream_t stream) {
  const int*   x        = (const int*)d_in[0];
  const float* emb      = (const float*)d_in[2];
  const float* enc_Wih  = (const float*)d_in[3];
  const float* enc_Whh  = (const float*)d_in[4];
  const float* enc_b    = (const float*)d_in[5];
  const float* att_fc_W = (const float*)d_in[6];
  const float* att_fc_b = (const float*)d_in[7];
  const float* att_w_W  = (const float*)d_in[8];
  const float* att_w_b  = (const float*)d_in[9];
  const float* dec_Wih  = (const float*)d_in[10];
  const float* dec_Whh  = (const float*)d_in[11];
  const float* dec_b    = (const float*)d_in[12];
  const float* fin_W    = (const float*)d_in[13];
  const float* fin_b    = (const float*)d_in[14];
  float* out = (float*)d_out;

  float* embW = (float*)d_ws;                              // 256000 f32
  unsigned short* decF = (unsigned short*)(embW + kV * kGE); // 34816 u16
  unsigned short* encF = decF + 17 * 4 * 64 * 8;           // 8192 u16
  unsigned short* afF  = encF + 16 * 2 * 64 * 8;           // 6144 u16
  float* dbias = (float*)(afF + 4 * 3 * 64 * 8);           // 264 f32
  float* abias = dbias + kGD;                              // 64
  float* ainit = abias + kHE;                              // 64

  prep_kernel<<<dim3(kV + 5), dim3(256), 0, stream>>>(
      emb, enc_Wih, enc_b, enc_Whh, att_fc_W, att_fc_b, fin_W, fin_b,
      dec_Wih, dec_Whh, dec_b, embW, decF, encF, afF, dbias, abias, ainit);
  enc_kernel<<<dim3(kB), dim3(256), 0, stream>>>(x, embW, encF, out);
  dec_kernel<<<dim3(kB), dim3(1024), 0, stream>>>(
      att_w_W, att_w_b, decF, afF, dbias, abias, ainit, out);
}

// Round 6
// 3489.161 us; speedup vs baseline: 1.3476x; 1.3206x over previous
//
#include <hip/hip_runtime.h>
#include <hip/hip_bf16.h>

#define kB 128
#define kS 1024
#define kT 512
#define kV 1000
#define kE 128
#define kHE 64
#define kHD 66
#define kATT 32
#define kGE 256   // 4*kHE
#define kGD 264   // 4*kHD

typedef __attribute__((ext_vector_type(4))) float f32x4;
typedef __attribute__((ext_vector_type(8))) short bf16x8;
typedef __attribute__((ext_vector_type(8))) unsigned short u16x8;

__device__ __forceinline__ unsigned short f2bf(float f) {
  unsigned int u = __builtin_bit_cast(unsigned int, f);
  u += 0x7FFFu + ((u >> 16) & 1u);
  return (unsigned short)(u >> 16);
}
__device__ __forceinline__ float rcp_(float x) { return __builtin_amdgcn_rcpf(x); }
__device__ __forceinline__ float fsig(float x)  { return rcp_(1.0f + __expf(-x)); }
__device__ __forceinline__ float ftanh(float x) { return 1.0f - 2.0f * rcp_(1.0f + __expf(2.0f * x)); }

// ---------------------------------------------------------------------------
// prep: embW (f32), bf16 MFMA B-fragments for enc_Whh / [dec_Wih|dec_Whh] / W_af,
// wregF (att_w_W per-lane f32 fragments, lane-consecutive), folded biases.
// Fragment layout: frag[((tile*KS + ks)*64 + lane)*8 + jj] =
// B[k = ks*32 + (lane>>4)*8 + jj][col = lane&15]  (col -> output index tile*16+col)
// ---------------------------------------------------------------------------
__global__ __launch_bounds__(256) void prep_kernel(
    const float* __restrict__ emb, const float* __restrict__ enc_Wih,
    const float* __restrict__ enc_b, const float* __restrict__ enc_Whh,
    const float* __restrict__ att_fc_W, const float* __restrict__ att_fc_b,
    const float* __restrict__ att_w_W,
    const float* __restrict__ fin_W, const float* __restrict__ fin_b,
    const float* __restrict__ dec_Wih, const float* __restrict__ dec_Whh,
    const float* __restrict__ dec_b,
    float* __restrict__ embW, unsigned short* __restrict__ decF,
    unsigned short* __restrict__ encF, unsigned short* __restrict__ afF,
    float* __restrict__ wregF, float* __restrict__ dbias,
    float* __restrict__ abias, float* __restrict__ ainit) {
  int bid = blockIdx.x, tid = threadIdx.x;
  if (bid < kV) {
    float acc = enc_b[tid];
    const float* er = emb + bid * kE;
    const float* wr = enc_Wih + tid * kE;
    for (int e = 0; e < kE; ++e) acc += er[e] * wr[e];
    embW[bid * kGE + tid] = acc;
  } else if (bid == kV) {
    // decF: 17 tiles x 4 ksteps, W = [dec_Wih | dec_Whh | 0pad], j<264
    for (int i = tid; i < 17 * 4 * 64 * 8; i += 256) {
      int jj = i & 7, lane = (i >> 3) & 63, ts = i >> 9;
      int tile = ts >> 2, ks = ts & 3;
      int j = tile * 16 + (lane & 15);
      int k = ks * 32 + ((lane >> 4) << 3) + jj;
      float v = 0.f;
      if (j < kGD) {
        if (k < 32) v = dec_Wih[j * kATT + k];
        else if (k < 98) v = dec_Whh[j * kHD + (k - 32)];
      }
      decF[i] = f2bf(v);
    }
  } else if (bid == kV + 1) {
    // encF: 16 tiles x 2 ksteps, B[k][j] = enc_Whh[j][k]
    for (int i = tid; i < 16 * 2 * 64 * 8; i += 256) {
      int jj = i & 7, lane = (i >> 3) & 63, ts = i >> 9;
      int tile = ts >> 1, ks = ts & 1;
      int j = tile * 16 + (lane & 15);
      int k = ks * 32 + ((lane >> 4) << 3) + jj;
      encF[i] = f2bf(enc_Whh[j * kHE + k]);
    }
  } else if (bid == kV + 2) {
    // afF: 4 tiles x 3 ksteps, B[m][aidx] = W_af[aidx][m] = sum_e att_fc_W[aidx][e] fin_W[e][m]
    for (int i = tid; i < 4 * 3 * 64 * 8; i += 256) {
      int jj = i & 7, lane = (i >> 3) & 63, ts = i >> 9;
      int tile = ts / 3, ks = ts - tile * 3;
      int aidx = tile * 16 + (lane & 15);
      int m = ks * 32 + ((lane >> 4) << 3) + jj;
      float v = 0.f;
      if (m < kHD)
        for (int e = 0; e < kE; ++e) v += att_fc_W[aidx * kE + e] * fin_W[e * kHD + m];
      afF[i] = f2bf(v);
    }
  } else if (bid == kV + 3) {
    // wregF[((mt*2+kc)*2+half)*256 + lane*4 + c] = att_w_W[mt*16+(lane&15)][kc*32+(lane>>4)*8+half*4+c]
    for (int i = tid; i < 8 * 64 * 4; i += 256) {
      int c = i & 3, lane = (i >> 2) & 63, jq = i >> 8;
      int half = jq & 1, kc = (jq >> 1) & 1, mt = jq >> 2;
      wregF[i] = att_w_W[(mt * 16 + (lane & 15)) * kHE + kc * 32 + ((lane >> 4) << 3) + half * 4 + c];
    }
  } else if (bid == kV + 4) {
    // dbias' = dec_b + 32 * rowsum(dec_Wih)   (beta fed centered at 32)
    // kGD=264 > 256 threads -> strided loop (R3 bug)
    for (int j = tid; j < kGD; j += 256) {
      float s = 0.f;
      for (int m = 0; m < kATT; ++m) s += dec_Wih[j * kATT + m];
      dbias[j] = dec_b[j] + 32.0f * s;
    }
  } else {
    if (tid < kHE) {
      float acc = att_fc_b[tid];
      for (int e = 0; e < kE; ++e) acc += att_fc_W[tid * kE + e] * fin_b[e];
      abias[tid] = acc;
    } else if (tid < 2 * kHE) {
      int a = tid - kHE;
      float acc = att_fc_b[a];
      for (int e = 0; e < kE; ++e) acc += emb[e] * att_fc_W[a * kE + e];
      ainit[a] = acc;
    }
  }
}

// ---------------------------------------------------------------------------
// encoder: 1 block / batch element, 256 threads (4 waves x 4 tiles).
// Writes swizzled bf16 h-states into out[b-region] (decoder stages from there,
// and overwrites it afterwards -- deterministic per replay).
// ---------------------------------------------------------------------------
__global__ __launch_bounds__(256, 1) void enc_kernel(
    const int* __restrict__ x, const float* __restrict__ embW,
    const unsigned short* __restrict__ encF, float* __restrict__ out) {
  __shared__ struct __align__(16) {
    unsigned short xe[64];
    float gbuf[kGE];
    int toks[kS];
  } sm;
  const int b = blockIdx.x, t = threadIdx.x, lane = t & 63, wv = t >> 6;

  for (int i = t; i < kS; i += 256) sm.toks[i] = x[b * kS + i];
  if (t < 64) sm.xe[t] = 0;

  u16x8 eQ[4][2];
  #pragma unroll
  for (int q = 0; q < 4; ++q)
    #pragma unroll
    for (int ks = 0; ks < 2; ++ks)
      eQ[q][ks] = *(const u16x8*)&encF[(((wv * 4 + q) * 2 + ks) * 64 + lane) * 8];
  __syncthreads();

  float gx0 = 0, gx1 = 0, gx2 = 0, gx3 = 0;
  if (lane < 16) {
    int tok = sm.toks[0];
    gx0 = embW[tok * kGE + wv * 64 + 0 + lane];
    gx1 = embW[tok * kGE + wv * 64 + 16 + lane];
    gx2 = embW[tok * kGE + wv * 64 + 32 + lane];
    gx3 = embW[tok * kGE + wv * 64 + 48 + lane];
  }
  float cE = 0.0f;
  unsigned short* eg = (unsigned short*)(out + (size_t)b * (kT * kHD));

  for (int s = 0; s < kS; ++s) {
    union { u16x8 u; bf16x8 v; } xa0, xa1;
    xa0.u = *(const u16x8*)&sm.xe[(lane >> 4) << 3];
    xa1.u = *(const u16x8*)&sm.xe[32 + ((lane >> 4) << 3)];
    // prefetch next-token input transforms
    float gn0 = 0, gn1 = 0, gn2 = 0, gn3 = 0;
    int tokn = sm.toks[(s + 1 < kS) ? (s + 1) : s];
    if (lane < 16) {
      gn0 = embW[tokn * kGE + wv * 64 + 0 + lane];
      gn1 = embW[tokn * kGE + wv * 64 + 16 + lane];
      gn2 = embW[tokn * kGE + wv * 64 + 32 + lane];
      gn3 = embW[tokn * kGE + wv * 64 + 48 + lane];
    }
    f32x4 z = {0.f, 0.f, 0.f, 0.f};
    f32x4 a0 = __builtin_amdgcn_mfma_f32_16x16x32_bf16(xa0.v, eQ[0][0], z, 0, 0, 0);
    a0 = __builtin_amdgcn_mfma_f32_16x16x32_bf16(xa1.v, eQ[0][1], a0, 0, 0, 0);
    f32x4 a1 = __builtin_amdgcn_mfma_f32_16x16x32_bf16(xa0.v, eQ[1][0], z, 0, 0, 0);
    a1 = __builtin_amdgcn_mfma_f32_16x16x32_bf16(xa1.v, eQ[1][1], a1, 0, 0, 0);
    f32x4 a2 = __builtin_amdgcn_mfma_f32_16x16x32_bf16(xa0.v, eQ[2][0], z, 0, 0, 0);
    a2 = __builtin_amdgcn_mfma_f32_16x16x32_bf16(xa1.v, eQ[2][1], a2, 0, 0, 0);
    f32x4 a3 = __builtin_amdgcn_mfma_f32_16x16x32_bf16(xa0.v, eQ[3][0], z, 0, 0, 0);
    a3 = __builtin_amdgcn_mfma_f32_16x16x32_bf16(xa1.v, eQ[3][1], a3, 0, 0, 0);
    if (lane < 16) {
      sm.gbuf[wv * 64 + 0 + lane]  = a0[0] + gx0;
      sm.gbuf[wv * 64 + 16 + lane] = a1[0] + gx1;
      sm.gbuf[wv * 64 + 32 + lane] = a2[0] + gx2;
      sm.gbuf[wv * 64 + 48 + lane] = a3[0] + gx3;
    }
    __syncthreads();
    if (t < 64) {
      float gi = sm.gbuf[t], gf = sm.gbuf[64 + t], gg = sm.gbuf[128 + t], go = sm.gbuf[192 + t];
      cE = fsig(gf) * cE + fsig(gi) * ftanh(gg);
      float h = fsig(go) * ftanh(cE);
      unsigned short hb = f2bf(h);
      sm.xe[t] = hb;
      eg[s * 64 + ((((t >> 3) ^ (s & 7)) << 3) | (t & 7))] = hb;
    }
    __syncthreads();
    gx0 = gn0; gx1 = gn1; gx2 = gn2; gx3 = gn3;
  }
}

// ---------------------------------------------------------------------------
// decoder: 1 block / batch element, 1024 threads (16 waves).
// __launch_bounds__(1024, 4): 4 waves/EU = 16 waves/CU = exactly 1 block ->
// VGPR cap 128 (R4: default heuristic targeted 2 blocks/CU -> 64 VGPRs ->
// all fragment arrays spilled to scratch; WRITE_SIZE showed +31MB scratch).
// att_w_W fragments live in LDS (wregL), read per step: persistent regs ~40.
// ---------------------------------------------------------------------------
struct __align__(16) DSm {
  unsigned short enc[kS * kHE];   // 131072 B  swizzled bf16
  float wregL[8 * 64 * 4];        // 8192 B    att_w_W lane fragments, lane-consecutive
  unsigned short xv[128];         // x-vector: [beta-32 (32) | h (66) | 0 pad]
  float aa[64];
  float betaW[16][32];
  float gbuf[kGD];
};  // ~143 KB

__global__ __launch_bounds__(1024, 4) void dec_kernel(
    const float* __restrict__ att_w_b,
    const unsigned short* __restrict__ decF, const unsigned short* __restrict__ afF,
    const float* __restrict__ wregF_ws, const float* __restrict__ dbias_ws,
    const float* __restrict__ abias_ws, const float* __restrict__ ainit_ws,
    float* __restrict__ out) {
  __shared__ DSm sm;
  const int b = blockIdx.x, t = threadIdx.x, lane = t & 63, wv = t >> 6;
  const int lr = lane & 15, g = lane >> 4;

  // stage encoder states (written by enc_kernel into this b's out region)
  {
    const u16x8* src = (const u16x8*)(out + (size_t)b * (kT * kHD));
    u16x8* dst = (u16x8*)sm.enc;
    #pragma unroll
    for (int i = 0; i < 8; ++i) dst[t + i * 1024] = src[t + i * 1024];
  }
  for (int i = t; i < 8 * 64 * 4; i += 1024) sm.wregL[i] = wregF_ws[i];

  float wbreg[2][4];
  #pragma unroll
  for (int mt = 0; mt < 2; ++mt)
    #pragma unroll
    for (int r = 0; r < 4; ++r) wbreg[mt][r] = att_w_b[mt * 16 + g * 4 + r];

  u16x8 dQ[4], dQ2[4], aQ[3];
  #pragma unroll
  for (int ks = 0; ks < 4; ++ks)
    dQ[ks] = *(const u16x8*)&decF[((wv * 4 + ks) * 64 + lane) * 8];
  if (wv == 8) {            // 17th tile on a wave that holds neither aQ nor much else
    #pragma unroll
    for (int ks = 0; ks < 4; ++ks)
      dQ2[ks] = *(const u16x8*)&decF[((16 * 4 + ks) * 64 + lane) * 8];
  }
  if (wv < 4) {
    #pragma unroll
    for (int ks = 0; ks < 3; ++ks)
      aQ[ks] = *(const u16x8*)&afF[((wv * 3 + ks) * 64 + lane) * 8];
  }
  float dbr = (lane < 16) ? dbias_ws[wv * 16 + lane] : 0.f;
  float dbr2 = (wv == 8 && lane < 8) ? dbias_ws[256 + lane] : 0.f;
  float abr = (wv < 4 && lane < 16) ? abias_ws[wv * 16 + lane] : 0.f;

  if (t < 128) sm.xv[t] = 0;
  if (t < 64) sm.aa[t] = ainit_ws[t];
  float cD = 0.0f;
  __syncthreads();

  const int sbase = wv * 64;
  for (int step = 0; step < kT; ++step) {
    // ---- P1: attention sweep (scores + softmax + beta partials), all 16 waves
    {
      const f32x4* aap = (const f32x4*)sm.aa;
      const f32x4* wrl = (const f32x4*)sm.wregL;   // [8][64] f32x4, index jq*64+lane
      bf16x8 af[2][2];
      #pragma unroll
      for (int kc = 0; kc < 2; ++kc) {
        f32x4 a0v = aap[kc * 8 + g * 2];
        f32x4 a1v = aap[kc * 8 + g * 2 + 1];
        #pragma unroll
        for (int mt = 0; mt < 2; ++mt) {
          f32x4 w0 = wrl[((mt * 2 + kc) * 2 + 0) * 64 + lane];
          f32x4 w1 = wrl[((mt * 2 + kc) * 2 + 1) * 64 + lane];
          union { bf16x8 v; __hip_bfloat162 h2[4]; } tmp;
          tmp.h2[0] = __float22bfloat162_rn(make_float2(w0.x * a0v.x, w0.y * a0v.y));
          tmp.h2[1] = __float22bfloat162_rn(make_float2(w0.z * a0v.z, w0.w * a0v.w));
          tmp.h2[2] = __float22bfloat162_rn(make_float2(w1.x * a1v.x, w1.y * a1v.y));
          tmp.h2[3] = __float22bfloat162_rn(make_float2(w1.z * a1v.z, w1.w * a1v.w));
          af[mt][kc] = tmp.v;
        }
      }
      float betaAcc[2][4] = {};
      float amax = 0.0f;
      #pragma unroll
      for (int nt = 0; nt < 4; ++nt) {
        int s = sbase + nt * 16 + lr;
        int sw = s & 7;
        union { u16x8 u; bf16x8 bv; } e0, e1;
        e0.u = *(const u16x8*)&sm.enc[s * kHE + ((g ^ sw) << 3)];
        e1.u = *(const u16x8*)&sm.enc[s * kHE + (((4 + g) ^ sw) << 3)];
        f32x4 z = {0.f, 0.f, 0.f, 0.f};
        f32x4 acc0 = __builtin_amdgcn_mfma_f32_16x16x32_bf16(af[0][0], e0.bv, z, 0, 0, 0);
        acc0 = __builtin_amdgcn_mfma_f32_16x16x32_bf16(af[0][1], e1.bv, acc0, 0, 0, 0);
        f32x4 acc1 = __builtin_amdgcn_mfma_f32_16x16x32_bf16(af[1][0], e0.bv, z, 0, 0, 0);
        acc1 = __builtin_amdgcn_mfma_f32_16x16x32_bf16(af[1][1], e1.bv, acc1, 0, 0, 0);
        float u0[4], u1[4], dsum = 0.f;
        #pragma unroll
        for (int r = 0; r < 4; ++r) {
          float x0 = acc0[r] + wbreg[0][r];
          float x1 = acc1[r] + wbreg[1][r];
          amax = fmaxf(amax, fmaxf(__builtin_fabsf(x0), __builtin_fabsf(x1)));
          u0[r] = __expf(x0 * __builtin_fmaf(x0 * x0, -0.33333334f, 1.0f));
          u1[r] = __expf(x1 * __builtin_fmaf(x1 * x1, -0.33333334f, 1.0f));
          dsum += u0[r] + u1[r];
        }
        dsum += __shfl_xor(dsum, 16);
        dsum += __shfl_xor(dsum, 32);
        float invd = rcp_(dsum);
        #pragma unroll
        for (int r = 0; r < 4; ++r) {
          betaAcc[0][r] += u0[r] * invd;
          betaAcc[1][r] += u1[r] * invd;
        }
      }
      if (__builtin_expect(__any(amax > 0.35f), 0)) {
        #pragma unroll
        for (int mt = 0; mt < 2; ++mt)
          #pragma unroll
          for (int r = 0; r < 4; ++r) betaAcc[mt][r] = 0.f;
        for (int nt = 0; nt < 4; ++nt) {
          int s = sbase + nt * 16 + lr;
          int sw = s & 7;
          union { u16x8 u; bf16x8 bv; } e0, e1;
          e0.u = *(const u16x8*)&sm.enc[s * kHE + ((g ^ sw) << 3)];
          e1.u = *(const u16x8*)&sm.enc[s * kHE + (((4 + g) ^ sw) << 3)];
          f32x4 z = {0.f, 0.f, 0.f, 0.f};
          f32x4 acc0 = __builtin_amdgcn_mfma_f32_16x16x32_bf16(af[0][0], e0.bv, z, 0, 0, 0);
          acc0 = __builtin_amdgcn_mfma_f32_16x16x32_bf16(af[0][1], e1.bv, acc0, 0, 0, 0);
          f32x4 acc1 = __builtin_amdgcn_mfma_f32_16x16x32_bf16(af[1][0], e0.bv, z, 0, 0, 0);
          acc1 = __builtin_amdgcn_mfma_f32_16x16x32_bf16(af[1][1], e1.bv, acc1, 0, 0, 0);
          float u0[4], u1[4], dsum = 0.f;
          for (int r = 0; r < 4; ++r) {
            u0[r] = __expf(tanhf(acc0[r] + wbreg[0][r]));
            u1[r] = __expf(tanhf(acc1[r] + wbreg[1][r]));
            dsum += u0[r] + u1[r];
          }
          dsum += __shfl_xor(dsum, 16);
          dsum += __shfl_xor(dsum, 32);
          float invd = rcp_(dsum);
          for (int r = 0; r < 4; ++r) {
            betaAcc[0][r] += u0[r] * invd;
            betaAcc[1][r] += u1[r] * invd;
          }
        }
      }
      #pragma unroll
      for (int mt = 0; mt < 2; ++mt)
        #pragma unroll
        for (int r = 0; r < 4; ++r) {
          float v = betaAcc[mt][r];
          v += __shfl_xor(v, 1);
          v += __shfl_xor(v, 2);
          v += __shfl_xor(v, 4);
          v += __shfl_xor(v, 8);
          if (lr == 0) sm.betaW[wv][mt * 16 + g * 4 + r] = v;
        }
    }
    __syncthreads();
    // ---- P2: beta reduce -> xv (centered bf16)
    if (t < kATT) {
      float sb = 0.f;
      #pragma unroll
      for (int w = 0; w < 16; ++w) sb += sm.betaW[w][t];
      sm.xv[t] = f2bf(sb - 32.0f);
    }
    __syncthreads();
    // ---- P3: decoder gates via MFMA (wave w -> tile w; wave 8 also tile 16)
    {
      union { u16x8 u; bf16x8 v; } xg0, xg1, xg2, xg3;
      xg0.u = *(const u16x8*)&sm.xv[(g << 3)];
      xg1.u = *(const u16x8*)&sm.xv[32 + (g << 3)];
      xg2.u = *(const u16x8*)&sm.xv[64 + (g << 3)];
      xg3.u = *(const u16x8*)&sm.xv[96 + (g << 3)];
      f32x4 z = {0.f, 0.f, 0.f, 0.f};
      f32x4 ga = __builtin_amdgcn_mfma_f32_16x16x32_bf16(xg0.v, dQ[0], z, 0, 0, 0);
      ga = __builtin_amdgcn_mfma_f32_16x16x32_bf16(xg1.v, dQ[1], ga, 0, 0, 0);
      ga = __builtin_amdgcn_mfma_f32_16x16x32_bf16(xg2.v, dQ[2], ga, 0, 0, 0);
      ga = __builtin_amdgcn_mfma_f32_16x16x32_bf16(xg3.v, dQ[3], ga, 0, 0, 0);
      if (lane < 16) sm.gbuf[wv * 16 + lane] = ga[0] + dbr;
      if (wv == 8) {
        f32x4 gb = __builtin_amdgcn_mfma_f32_16x16x32_bf16(xg0.v, dQ2[0], z, 0, 0, 0);
        gb = __builtin_amdgcn_mfma_f32_16x16x32_bf16(xg1.v, dQ2[1], gb, 0, 0, 0);
        gb = __builtin_amdgcn_mfma_f32_16x16x32_bf16(xg2.v, dQ2[2], gb, 0, 0, 0);
        gb = __builtin_amdgcn_mfma_f32_16x16x32_bf16(xg3.v, dQ2[3], gb, 0, 0, 0);
        if (lane < 8) sm.gbuf[256 + lane] = gb[0] + dbr2;
      }
    }
    __syncthreads();
    // ---- P4: LSTM cell + output + h -> xv
    if (t < kHD) {
      float gi = sm.gbuf[t], gf = sm.gbuf[kHD + t], gg = sm.gbuf[2 * kHD + t], go = sm.gbuf[3 * kHD + t];
      cD = fsig(gf) * cD + fsig(gi) * ftanh(gg);
      float h = fsig(go) * ftanh(cD);
      sm.xv[32 + t] = f2bf(h);
      out[((size_t)b * kT + step) * kHD + t] = h;
    }
    __syncthreads();
    // ---- P5: a-update via MFMA (waves 0-3)
    if (wv < 4) {
      union { u16x8 u; bf16x8 v; } y0, y1, y2;
      y0.u = *(const u16x8*)&sm.xv[32 + (g << 3)];
      y1.u = *(const u16x8*)&sm.xv[64 + (g << 3)];
      y2.u = *(const u16x8*)&sm.xv[96 + (g << 3)];
      f32x4 z = {0.f, 0.f, 0.f, 0.f};
      f32x4 aacc = __builtin_amdgcn_mfma_f32_16x16x32_bf16(y0.v, aQ[0], z, 0, 0, 0);
      aacc = __builtin_amdgcn_mfma_f32_16x16x32_bf16(y1.v, aQ[1], aacc, 0, 0, 0);
      aacc = __builtin_amdgcn_mfma_f32_16x16x32_bf16(y2.v, aQ[2], aacc, 0, 0, 0);
      if (lane < 16) sm.aa[wv * 16 + lane] = aacc[0] + abr;
    }
    __syncthreads();
  }
}

extern "C" void kernel_launch(void* const* d_in, const int* in_sizes, int n_in,
                              void* d_out, int out_size, void* d_ws, size_t ws_size,
                              hipStream_t stream) {
  const int*   x        = (const int*)d_in[0];
  const float* emb      = (const float*)d_in[2];
  const float* enc_Wih  = (const float*)d_in[3];
  const float* enc_Whh  = (const float*)d_in[4];
  const float* enc_b    = (const float*)d_in[5];
  const float* att_fc_W = (const float*)d_in[6];
  const float* att_fc_b = (const float*)d_in[7];
  const float* att_w_W  = (const float*)d_in[8];
  const float* att_w_b  = (const float*)d_in[9];
  const float* dec_Wih  = (const float*)d_in[10];
  const float* dec_Whh  = (const float*)d_in[11];
  const float* dec_b    = (const float*)d_in[12];
  const float* fin_W    = (const float*)d_in[13];
  const float* fin_b    = (const float*)d_in[14];
  float* out = (float*)d_out;

  float* embW = (float*)d_ws;                                // 256000 f32
  unsigned short* decF = (unsigned short*)(embW + kV * kGE); // 34816 u16
  unsigned short* encF = decF + 17 * 4 * 64 * 8;             // 8192 u16
  unsigned short* afF  = encF + 16 * 2 * 64 * 8;             // 6144 u16
  float* wregF = (float*)(afF + 4 * 3 * 64 * 8);             // 2048 f32
  float* dbias = wregF + 8 * 64 * 4;                         // 264 f32
  float* abias = dbias + kGD;                                // 64
  float* ainit = abias + kHE;                                // 64

  prep_kernel<<<dim3(kV + 6), dim3(256), 0, stream>>>(
      emb, enc_Wih, enc_b, enc_Whh, att_fc_W, att_fc_b, att_w_W, fin_W, fin_b,
      dec_Wih, dec_Whh, dec_b, embW, decF, encF, afF, wregF, dbias, abias, ainit);
  enc_kernel<<<dim3(kB), dim3(256), 0, stream>>>(x, embW, encF, out);
  dec_kernel<<<dim3(kB), dim3(1024), 0, stream>>>(
      att_w_b, decF, afF, wregF, dbias, abias, ainit, out);
}